// Round 12
// baseline (265.327 us; speedup 1.0000x reference)
//
#include <hip/hip_runtime.h>

// VQ embedding, bf16-MFMA, frag-major dense B stream + packed uint argmin.
// z: (B=64, D=256, H=32, W=32) fp32; codebook: (K=1024, D=256) fp32.
// argmin_k ||z_n - c_k||^2 = argmin_k (1 + ||c_k||^2 - 2 z.c_k)   [shift keeps score > 0]
// Packed key: (float_bits(score) & 0xFFFFFC00) | k  -> uint min = argmin w/ first-index ties.
// Outputs (flat fp32): st[16777216] = chosen codebook row, indices[65536] as float,
// loss = 1.25 * (sum z^2 + sum (best_score - 1)).
//
// R12 = the R10/R11 TLP experiment (both died on infra with identical source),
// restructured: flat pointer-increment K-loop, B pair loaded right before the MFMA
// burst, no manual pipeline. __launch_bounds__(256,4) -> 128-unified-reg budget ->
// 4 blocks/CU (16 waves). Occupancy quantum (R9): slots step at <=64/<=128/<=256
// total regs; R6's 148 gave only 8 waves/CU. Compiler pipelines B as deep as fits
// (R4: its scheduling equals manual). Rest = R6 frontier: 64-row tile, codes-x4
// no-dup wave split, acc[4][2]+best[16], frag-major cbf.

#define IDX_OFF  16777216
#define LOSS_OFF 16842752

typedef __bf16 bf16x8 __attribute__((ext_vector_type(8)));
typedef float  f32x4  __attribute__((ext_vector_type(4)));

// ------- Kernel 1: cb fp32 -> bf16 row-major + frag-major copies + (1 + ||c||^2) -------
__global__ __launch_bounds__(256) void vq_prep(const float* __restrict__ cb,
                                               __bf16* __restrict__ cbh,
                                               __bf16* __restrict__ cbf,
                                               float* __restrict__ sc1) {
    const int t = threadIdx.x;
    const int r = blockIdx.x * 16 + (t >> 4);
    const int d0 = (t & 15) * 16;
    const float* src = cb + (size_t)r * 256 + d0;
    __bf16* dst = cbh + (size_t)r * 256 + d0;
    float s = 0.f;
    float4 f[4];
    #pragma unroll
    for (int p = 0; p < 4; p++) f[p] = *(const float4*)(src + p * 4);
    bf16x8 v0, v1;
    #pragma unroll
    for (int p = 0; p < 4; p++) {
        s = fmaf(f[p].x, f[p].x, s); s = fmaf(f[p].y, f[p].y, s);
        s = fmaf(f[p].z, f[p].z, s); s = fmaf(f[p].w, f[p].w, s);
    }
    v0[0]=(__bf16)f[0].x; v0[1]=(__bf16)f[0].y; v0[2]=(__bf16)f[0].z; v0[3]=(__bf16)f[0].w;
    v0[4]=(__bf16)f[1].x; v0[5]=(__bf16)f[1].y; v0[6]=(__bf16)f[1].z; v0[7]=(__bf16)f[1].w;
    v1[0]=(__bf16)f[2].x; v1[1]=(__bf16)f[2].y; v1[2]=(__bf16)f[2].z; v1[3]=(__bf16)f[2].w;
    v1[4]=(__bf16)f[3].x; v1[5]=(__bf16)f[3].y; v1[6]=(__bf16)f[3].z; v1[7]=(__bf16)f[3].w;
    *(bf16x8*)dst = v0;
    *(bf16x8*)(dst + 8) = v1;
    // frag-major: tile = r>>4, chunk = d0>>5, lane slot = (r&15)*4 + ((d0>>3)&3)
    {
        const int slot = ((r >> 4) * 8 + (d0 >> 5)) * 512 + ((r & 15) * 4 + ((d0 >> 3) & 3)) * 8;
        *(bf16x8*)&cbf[slot]     = v0;
        *(bf16x8*)&cbf[slot + 8] = v1;
    }
    s += __shfl_xor(s, 1, 64);
    s += __shfl_xor(s, 2, 64);
    s += __shfl_xor(s, 4, 64);
    s += __shfl_xor(s, 8, 64);
    if ((t & 15) == 0) sc1[r] = s + 1.0f;
}

// ---------------- Kernel 2: MFMA distance-GEMM + argmin + outputs ----------------
// Block: 64 n-rows x all 1024 codes. 4 waves: each wave all 64 rows (4 row-frags)
// x its own 32 codes (2 frags) of each 128-code chunk. LDS 32 KB z tile [64][256]
// bf16, XOR-swizzled; recycled as argmin scratch, then as chosen-q tile for
// coalesced emit. No barriers in K-loop. 1024 blocks, kt-rotated per block.
// Target: 4 blocks/CU (16 waves) under the 128-unified-reg quantum.
__global__ __launch_bounds__(256, 4) void vq_mfma(const float* __restrict__ z,
                                                  const __bf16* __restrict__ cbh,
                                                  const __bf16* __restrict__ cbf,
                                                  const float* __restrict__ sc1,
                                                  float* __restrict__ out) {
    __shared__ __align__(16) __bf16 z_s[64 * 256];    // 32768 B
    __shared__ float red_s[4];

    const int t    = threadIdx.x;
    const int lane = t & 63;
    const int w    = t >> 6;
    const int m16  = lane & 15;
    const int q4   = lane >> 4;
    const int wc   = w << 5;              // wave's code offset within a 128-chunk
    const int lidx = m16 * 4 + q4;        // frag-major lane slot
    const int blk  = blockIdx.x;
    const int b    = blk >> 4;
    const int hw0  = (blk & 15) << 6;
    const int n0   = blk << 6;
    const int kt0  = (blk & 3) << 8;      // rotated code-sweep start (desync L2 streams)

    // ---- phase A: stage z (fp32 global, float4 along hw) -> bf16 LDS [n][d]; sum z^2
    float lz = 0.f;
    {
        const int rg    = (t & 15) * 4;       // 4-row group
        const int dbase = (t >> 4) * 16;      // 16 d's per thread
        const float* zp = z + (size_t)b * 262144 + hw0 + rg;
        #pragma unroll
        for (int batch = 0; batch < 2; batch++) {
            float4 f[8];
            #pragma unroll
            for (int j = 0; j < 8; j++)
                f[j] = *(const float4*)(zp + (size_t)(dbase + batch * 8 + j) * 1024);
            const float* fp = (const float*)f;
            #pragma unroll
            for (int r = 0; r < 4; r++) {
                bf16x8 v;
                #pragma unroll
                for (int j = 0; j < 8; j++) {
                    float x = fp[j * 4 + r];
                    lz = fmaf(x, x, lz);
                    v[j] = (__bf16)x;
                }
                const int row = rg + r;
                const int gs  = ((t >> 4) * 2 + batch) ^ (row & 7);
                *(bf16x8*)&z_s[row * 256 + gs * 8] = v;
            }
        }
    }
    __syncthreads();

    // ---- GEMM + packed-uint running argmin (no barriers in K-loop; compiler
    //      software-pipelines the B loads as deep as the 128-reg budget allows)
    unsigned int best[16];
    #pragma unroll
    for (int i = 0; i < 16; i++) best[i] = 0xFFFFFFFFu;

    #pragma unroll 1
    for (int it = 0; it < 8; it++) {
        const int kt = (kt0 + (it << 7)) & 1023;
        // per-chunk code norms (+1) and packed indices — hidden under MFMAs
        int   kcv[2];
        float sck[2];
        #pragma unroll
        for (int j = 0; j < 2; j++) {
            kcv[j] = kt + wc + j * 16 + m16;
            sck[j] = sc1[kcv[j]];
        }
        // frag-major base for this wave's 32-code slice of chunk kt
        const __bf16* bp = cbf + ((kt + wc) >> 4) * 4096 + lidx * 8;

        f32x4 acc[4][2];
        #pragma unroll
        for (int i = 0; i < 4; i++)
            #pragma unroll
            for (int j = 0; j < 2; j++) acc[i][j] = (f32x4){0.f, 0.f, 0.f, 0.f};

        #pragma unroll
        for (int dcs = 0; dcs < 8; dcs++) {
            // B frag pair for this 32-d step (dense 1 KB bursts)
            const bf16x8 bb0 = *(const bf16x8*)(bp);
            const bf16x8 bb1 = *(const bf16x8*)(bp + 4096);
            bp += 512;

            // A frags in-place
            const int gs = (dcs * 4 + q4) ^ (m16 & 7);
            #pragma unroll
            for (int i = 0; i < 4; i++) {
                const bf16x8 a = *(const bf16x8*)&z_s[(i * 16 + m16) * 256 + gs * 8];
                acc[i][0] = __builtin_amdgcn_mfma_f32_16x16x32_bf16(a, bb0, acc[i][0], 0, 0, 0);
                acc[i][1] = __builtin_amdgcn_mfma_f32_16x16x32_bf16(a, bb1, acc[i][1], 0, 0, 0);
            }
        }

        // packed argmin: score = 1 + ||c||^2 - 2 z.c  > 0 always
        #pragma unroll
        for (int j = 0; j < 2; j++) {
            #pragma unroll
            for (int i = 0; i < 4; i++)
                #pragma unroll
                for (int r = 0; r < 4; r++) {
                    float v3 = fmaf(-2.f, acc[i][j][r], sck[j]);
                    unsigned int key = (__float_as_uint(v3) & 0xFFFFFC00u) | (unsigned int)kcv[j];
                    int pos = i * 4 + r;
                    best[pos] = min(best[pos], key);
                }
        }
    }

    // ---- intra-wave min across the 16 col-lanes
    #pragma unroll
    for (int pos = 0; pos < 16; pos++) {
        unsigned int k = best[pos];
        #pragma unroll
        for (int off = 1; off < 16; off <<= 1)
            k = min(k, (unsigned int)__shfl_xor((int)k, off, 64));
        best[pos] = k;
    }
    __syncthreads();              // all z_s reads done -> z_s becomes scratch

    // ---- cross-wave combine in recycled z_s
    // ks[0..256): key[wave][row] (each wave owns a distinct code quarter);
    // ks[256..320): chosen k
    unsigned int* ks = (unsigned int*)z_s;
    if (m16 == 0) {
        #pragma unroll
        for (int pos = 0; pos < 16; pos++) {
            int i = pos >> 2, r = pos & 3;
            int row = i * 16 + q4 * 4 + r;
            ks[w * 64 + row] = best[pos];
        }
    }
    __syncthreads();
    if (t < 64) {
        unsigned int key = min(min(ks[t], ks[64 + t]), min(ks[128 + t], ks[192 + t]));
        int kf = (int)(key & 1023u);
        ks[256 + t] = (unsigned int)kf;
        out[IDX_OFF + n0 + t] = (float)kf;
        lz += __uint_as_float(key & 0xFFFFFC00u) - 1.0f;   // best score (unshifted)
    }
    {
        float s = lz;
        #pragma unroll
        for (int off = 1; off < 64; off <<= 1) s += __shfl_xor(s, off, 64);
        if (lane == 0) red_s[w] = s;
    }
    __syncthreads();              // ks[256..320) and red_s visible
    if (t == 0)
        atomicAdd(out + LOSS_OFF, 1.25f * ((red_s[0] + red_s[1]) + (red_s[2] + red_s[3])));

    // ---- stage chosen codebook rows into z_s, then coalesced emit
    const int qrow = t >> 2;              // 0..63
    const int qoff = (t & 3) * 64;        // d offset 0/64/128/192
    const int myk  = (int)ks[256 + qrow];
    __syncthreads();              // everyone read their k; safe to overwrite z_s
    {
        const __bf16* qp = cbh + (size_t)myk * 256 + qoff;
        #pragma unroll
        for (int p = 0; p < 8; p++) {
            bf16x8 v = *(const bf16x8*)(qp + p * 8);
            int gs = ((qoff >> 3) + p) ^ (qrow & 7);
            *(bf16x8*)&z_s[qrow * 256 + gs * 8] = v;
        }
    }
    __syncthreads();
    {
        const int nl   = t & 63;
        const int dseg = t >> 6;
        float* op = out + (size_t)(b * 256 + dseg * 64) * 1024 + hw0 + nl;
        #pragma unroll
        for (int p = 0; p < 8; p++) {
            int gs = (dseg * 8 + p) ^ (nl & 7);
            bf16x8 v = *(const bf16x8*)&z_s[nl * 256 + gs * 8];
            #pragma unroll
            for (int j = 0; j < 8; j++)
                op[(size_t)(p * 8 + j) * 1024] = (float)v[j];
        }
    }
}

extern "C" void kernel_launch(void* const* d_in, const int* in_sizes, int n_in,
                              void* d_out, int out_size, void* d_ws, size_t ws_size,
                              hipStream_t stream) {
    const float* z  = (const float*)d_in[0];   // 16777216
    const float* cb = (const float*)d_in[1];   // 262144
    float* out = (float*)d_out;

    float*  sc1 = (float*)d_ws;                             // 1024 f  (1 + ||c||^2)
    __bf16* cbh = (__bf16*)((char*)d_ws + 8192);            // 512 KB bf16 codebook (row-major)
    __bf16* cbf = (__bf16*)((char*)d_ws + 8192 + 524288);   // 512 KB bf16 codebook (frag-major)

    hipMemsetAsync(out + LOSS_OFF, 0, sizeof(float), stream);   // capture-safe
    vq_prep<<<64, 256, 0, stream>>>(cb, cbh, cbf, sc1);
    vq_mfma<<<1024, 256, 0, stream>>>(z, cbh, cbf, sc1, out);
}

// Round 13
// 161.878 us; speedup vs baseline: 1.6391x; 1.6391x over previous
//
#include <hip/hip_runtime.h>

// VQ embedding, bf16-MFMA, frag-major dense B stream + packed uint argmin.
// z: (B=64, D=256, H=32, W=32) fp32; codebook: (K=1024, D=256) fp32.
// argmin_k ||z_n - c_k||^2 = argmin_k (1 + ||c_k||^2 - 2 z.c_k)   [shift keeps score > 0]
// Packed key: (float_bits(score) & 0xFFFFFC00) | k  -> uint min = argmin w/ first-index ties.
// Outputs (flat fp32): st[16777216] = chosen codebook row, indices[65536] as float,
// loss = 1.25 * (sum z^2 + sum (best_score - 1)).
//
// R13 = R6 frontier (75 us) with the kt0 sweep rotation REMOVED (never ablated;
// introduced alongside R3's dedup win). Rationale: codebook (512 KB) fits every
// XCD L2, so rotation protects nothing — but it guarantees the 2 co-resident
// blocks/CU never overlap their B-streams temporally, killing L1 reuse. Synced
// sweeps make block1's B-loads hit lines block0 just fetched (L1/L2-hot),
// halving the per-CU cold-request rate — the quantity time has tracked all
// session (R2->R3->R6). TLP closed (R12: 128-reg quantum unreachable, 3rd spill).

#define IDX_OFF  16777216
#define LOSS_OFF 16842752

typedef __bf16 bf16x8 __attribute__((ext_vector_type(8)));
typedef float  f32x4  __attribute__((ext_vector_type(4)));

// ------- Kernel 1: cb fp32 -> bf16 row-major + frag-major copies + (1 + ||c||^2) -------
__global__ __launch_bounds__(256) void vq_prep(const float* __restrict__ cb,
                                               __bf16* __restrict__ cbh,
                                               __bf16* __restrict__ cbf,
                                               float* __restrict__ sc1) {
    const int t = threadIdx.x;
    const int r = blockIdx.x * 16 + (t >> 4);
    const int d0 = (t & 15) * 16;
    const float* src = cb + (size_t)r * 256 + d0;
    __bf16* dst = cbh + (size_t)r * 256 + d0;
    float s = 0.f;
    float4 f[4];
    #pragma unroll
    for (int p = 0; p < 4; p++) f[p] = *(const float4*)(src + p * 4);
    bf16x8 v0, v1;
    #pragma unroll
    for (int p = 0; p < 4; p++) {
        s = fmaf(f[p].x, f[p].x, s); s = fmaf(f[p].y, f[p].y, s);
        s = fmaf(f[p].z, f[p].z, s); s = fmaf(f[p].w, f[p].w, s);
    }
    v0[0]=(__bf16)f[0].x; v0[1]=(__bf16)f[0].y; v0[2]=(__bf16)f[0].z; v0[3]=(__bf16)f[0].w;
    v0[4]=(__bf16)f[1].x; v0[5]=(__bf16)f[1].y; v0[6]=(__bf16)f[1].z; v0[7]=(__bf16)f[1].w;
    v1[0]=(__bf16)f[2].x; v1[1]=(__bf16)f[2].y; v1[2]=(__bf16)f[2].z; v1[3]=(__bf16)f[2].w;
    v1[4]=(__bf16)f[3].x; v1[5]=(__bf16)f[3].y; v1[6]=(__bf16)f[3].z; v1[7]=(__bf16)f[3].w;
    *(bf16x8*)dst = v0;
    *(bf16x8*)(dst + 8) = v1;
    // frag-major: tile = r>>4, chunk = d0>>5, lane slot = (r&15)*4 + ((d0>>3)&3)
    {
        const int slot = ((r >> 4) * 8 + (d0 >> 5)) * 512 + ((r & 15) * 4 + ((d0 >> 3) & 3)) * 8;
        *(bf16x8*)&cbf[slot]     = v0;
        *(bf16x8*)&cbf[slot + 8] = v1;
    }
    s += __shfl_xor(s, 1, 64);
    s += __shfl_xor(s, 2, 64);
    s += __shfl_xor(s, 4, 64);
    s += __shfl_xor(s, 8, 64);
    if ((t & 15) == 0) sc1[r] = s + 1.0f;
}

// ---------------- Kernel 2: MFMA distance-GEMM + argmin + outputs ----------------
// Block: 64 n-rows x all 1024 codes. 4 waves: each wave all 64 rows (4 row-frags)
// x its own 32 codes (2 frags) of each 128-code chunk. LDS 32 KB z tile [64][256]
// bf16, XOR-swizzled; recycled as argmin scratch, then as chosen-q tile for
// coalesced emit. No barriers in K-loop. 1024 blocks, ALL blocks sweep codes in
// the same order (synced for L1/L2 temporal reuse between co-resident blocks).
__global__ __launch_bounds__(256, 2) void vq_mfma(const float* __restrict__ z,
                                                  const __bf16* __restrict__ cbh,
                                                  const __bf16* __restrict__ cbf,
                                                  const float* __restrict__ sc1,
                                                  float* __restrict__ out) {
    __shared__ __align__(16) __bf16 z_s[64 * 256];    // 32768 B
    __shared__ float red_s[4];

    const int t    = threadIdx.x;
    const int lane = t & 63;
    const int w    = t >> 6;
    const int m16  = lane & 15;
    const int q4   = lane >> 4;
    const int wc   = w << 5;              // wave's code offset within a 128-chunk
    const int lidx = m16 * 4 + q4;        // frag-major lane slot
    const int blk  = blockIdx.x;
    const int b    = blk >> 4;
    const int hw0  = (blk & 15) << 6;
    const int n0   = blk << 6;

    // B preload: first chunk's frag pair (dense 1 KB bursts), in flight during phase A
    bf16x8 bb[2];
    {
        const __bf16* bp = cbf + (size_t)(wc >> 4) * 4096 + lidx * 8;
        bb[0] = *(const bf16x8*)bp;
        bb[1] = *(const bf16x8*)(bp + 4096);
    }

    // ---- phase A: stage z (fp32 global, float4 along hw) -> bf16 LDS [n][d]; sum z^2
    float lz = 0.f;
    {
        const int rg    = (t & 15) * 4;       // 4-row group
        const int dbase = (t >> 4) * 16;      // 16 d's per thread
        const float* zp = z + (size_t)b * 262144 + hw0 + rg;
        #pragma unroll
        for (int batch = 0; batch < 2; batch++) {
            float4 f[8];
            #pragma unroll
            for (int j = 0; j < 8; j++)
                f[j] = *(const float4*)(zp + (size_t)(dbase + batch * 8 + j) * 1024);
            const float* fp = (const float*)f;
            #pragma unroll
            for (int r = 0; r < 4; r++) {
                bf16x8 v;
                #pragma unroll
                for (int j = 0; j < 8; j++) {
                    float x = fp[j * 4 + r];
                    lz = fmaf(x, x, lz);
                    v[j] = (__bf16)x;
                }
                const int row = rg + r;
                const int gs  = ((t >> 4) * 2 + batch) ^ (row & 7);
                *(bf16x8*)&z_s[row * 256 + gs * 8] = v;
            }
        }
    }
    __syncthreads();

    // ---- GEMM + packed-uint running argmin (no barriers in K-loop)
    unsigned int best[16];
    #pragma unroll
    for (int i = 0; i < 16; i++) best[i] = 0xFFFFFFFFu;

    #pragma unroll 1
    for (int it = 0; it < 8; it++) {
        const int kt  = it << 7;
        const int ktn = ((it + 1) & 7) << 7;
        // per-chunk code norms (+1) and packed indices — hidden under MFMAs
        int   kcv[2];
        float sck[2];
        #pragma unroll
        for (int j = 0; j < 2; j++) {
            kcv[j] = kt + wc + j * 16 + m16;
            sck[j] = sc1[kcv[j]];
        }
        // frag-major bases: tile stride 4096 elems, chunk stride 512 elems (compile-time)
        const __bf16* bt  = cbf + (size_t)((kt  + wc) >> 4) * 4096 + lidx * 8;
        const __bf16* btn = cbf + (size_t)((ktn + wc) >> 4) * 4096 + lidx * 8;

        f32x4 acc[4][2];
        #pragma unroll
        for (int i = 0; i < 4; i++)
            #pragma unroll
            for (int j = 0; j < 2; j++) acc[i][j] = (f32x4){0.f, 0.f, 0.f, 0.f};

        #pragma unroll
        for (int dcs = 0; dcs < 8; dcs++) {
            const int dc = dcs * 32;
            // B prefetch 1 chunk ahead (next kt's chunk 0 on the last step)
            bf16x8 bn[2];
            const __bf16* bp = (dcs < 7) ? (bt + (dcs + 1) * 512) : btn;
            bn[0] = *(const bf16x8*)bp;
            bn[1] = *(const bf16x8*)(bp + 4096);

            // A frags in-place (compiler schedules fine per R4 null)
            const int gs = ((dc >> 3) + q4) ^ (m16 & 7);
            #pragma unroll
            for (int i = 0; i < 4; i++) {
                bf16x8 a = *(const bf16x8*)&z_s[(i * 16 + m16) * 256 + gs * 8];
                acc[i][0] = __builtin_amdgcn_mfma_f32_16x16x32_bf16(a, bb[0], acc[i][0], 0, 0, 0);
                acc[i][1] = __builtin_amdgcn_mfma_f32_16x16x32_bf16(a, bb[1], acc[i][1], 0, 0, 0);
            }

            bb[0] = bn[0];
            bb[1] = bn[1];
        }

        // packed argmin: score = 1 + ||c||^2 - 2 z.c  > 0 always
        #pragma unroll
        for (int j = 0; j < 2; j++) {
            #pragma unroll
            for (int i = 0; i < 4; i++)
                #pragma unroll
                for (int r = 0; r < 4; r++) {
                    float v3 = fmaf(-2.f, acc[i][j][r], sck[j]);
                    unsigned int key = (__float_as_uint(v3) & 0xFFFFFC00u) | (unsigned int)kcv[j];
                    int pos = i * 4 + r;
                    best[pos] = min(best[pos], key);
                }
        }
    }

    // ---- intra-wave min across the 16 col-lanes
    #pragma unroll
    for (int pos = 0; pos < 16; pos++) {
        unsigned int k = best[pos];
        #pragma unroll
        for (int off = 1; off < 16; off <<= 1)
            k = min(k, (unsigned int)__shfl_xor((int)k, off, 64));
        best[pos] = k;
    }
    __syncthreads();              // all z_s reads done -> z_s becomes scratch

    // ---- cross-wave combine in recycled z_s
    // ks[0..256): key[wave][row] (each wave owns a distinct code quarter);
    // ks[256..320): chosen k
    unsigned int* ks = (unsigned int*)z_s;
    if (m16 == 0) {
        #pragma unroll
        for (int pos = 0; pos < 16; pos++) {
            int i = pos >> 2, r = pos & 3;
            int row = i * 16 + q4 * 4 + r;
            ks[w * 64 + row] = best[pos];
        }
    }
    __syncthreads();
    if (t < 64) {
        unsigned int key = min(min(ks[t], ks[64 + t]), min(ks[128 + t], ks[192 + t]));
        int kf = (int)(key & 1023u);
        ks[256 + t] = (unsigned int)kf;
        out[IDX_OFF + n0 + t] = (float)kf;
        lz += __uint_as_float(key & 0xFFFFFC00u) - 1.0f;   // best score (unshifted)
    }
    {
        float s = lz;
        #pragma unroll
        for (int off = 1; off < 64; off <<= 1) s += __shfl_xor(s, off, 64);
        if (lane == 0) red_s[w] = s;
    }
    __syncthreads();              // ks[256..320) and red_s visible
    if (t == 0)
        atomicAdd(out + LOSS_OFF, 1.25f * ((red_s[0] + red_s[1]) + (red_s[2] + red_s[3])));

    // ---- stage chosen codebook rows into z_s, then coalesced emit
    const int qrow = t >> 2;              // 0..63
    const int qoff = (t & 3) * 64;        // d offset 0/64/128/192
    const int myk  = (int)ks[256 + qrow];
    __syncthreads();              // everyone read their k; safe to overwrite z_s
    {
        const __bf16* qp = cbh + (size_t)myk * 256 + qoff;
        #pragma unroll
        for (int p = 0; p < 8; p++) {
            bf16x8 v = *(const bf16x8*)(qp + p * 8);
            int gs = ((qoff >> 3) + p) ^ (qrow & 7);
            *(bf16x8*)&z_s[qrow * 256 + gs * 8] = v;
        }
    }
    __syncthreads();
    {
        const int nl   = t & 63;
        const int dseg = t >> 6;
        float* op = out + (size_t)(b * 256 + dseg * 64) * 1024 + hw0 + nl;
        #pragma unroll
        for (int p = 0; p < 8; p++) {
            int gs = (dseg * 8 + p) ^ (nl & 7);
            bf16x8 v = *(const bf16x8*)&z_s[nl * 256 + gs * 8];
            #pragma unroll
            for (int j = 0; j < 8; j++)
                op[(size_t)(p * 8 + j) * 1024] = (float)v[j];
        }
    }
}

extern "C" void kernel_launch(void* const* d_in, const int* in_sizes, int n_in,
                              void* d_out, int out_size, void* d_ws, size_t ws_size,
                              hipStream_t stream) {
    const float* z  = (const float*)d_in[0];   // 16777216
    const float* cb = (const float*)d_in[1];   // 262144
    float* out = (float*)d_out;

    float*  sc1 = (float*)d_ws;                             // 1024 f  (1 + ||c||^2)
    __bf16* cbh = (__bf16*)((char*)d_ws + 8192);            // 512 KB bf16 codebook (row-major)
    __bf16* cbf = (__bf16*)((char*)d_ws + 8192 + 524288);   // 512 KB bf16 codebook (frag-major)

    hipMemsetAsync(out + LOSS_OFF, 0, sizeof(float), stream);   // capture-safe
    vq_prep<<<64, 256, 0, stream>>>(cb, cbh, cbf, sc1);
    vq_mfma<<<1024, 256, 0, stream>>>(z, cbh, cbf, sc1, out);
}

// Round 14
// 154.627 us; speedup vs baseline: 1.7159x; 1.0469x over previous
//
#include <hip/hip_runtime.h>

// VQ embedding, bf16-MFMA, frag-major dense B stream + packed uint argmin.
// z: (B=64, D=256, H=32, W=32) fp32; codebook: (K=1024, D=256) fp32.
// argmin_k ||z_n - c_k||^2 = argmin_k (1 + ||c_k||^2 - 2 z.c_k)   [shift keeps score > 0]
// Packed key: (float_bits(score) & 0xFFFFFC00) | k  -> uint min = argmin w/ first-index ties.
// Outputs (flat fp32): st[16777216] = chosen codebook row, indices[65536] as float,
// loss = 1.25 * (sum z^2 + sum (best_score - 1)).
//
// R14 = R6 frontier (75 us) + 4-deep B prefetch pipeline (bq[4][2], full-unroll
// rotation). Rationale: occupancy quantum (R9/R12) means R6's ~148 unified regs
// already occupy the 256-reg slot -> ~100 regs are free. R4's "prefetch null" was
// measured in the SCATTERED B regime (request-rate wall); R6's dense stream left a
// pure ~200cyc L2 latency stall (per-step coverage ~50cyc -> MfmaUtil 17.5%,
// matching 40/190 arithmetic). 4-deep = ~200cyc coverage. kt0 rotation restored
// (R13: removal cost ~8 us). Everything else bit-identical to R6.

#define IDX_OFF  16777216
#define LOSS_OFF 16842752

typedef __bf16 bf16x8 __attribute__((ext_vector_type(8)));
typedef float  f32x4  __attribute__((ext_vector_type(4)));

// ------- Kernel 1: cb fp32 -> bf16 row-major + frag-major copies + (1 + ||c||^2) -------
__global__ __launch_bounds__(256) void vq_prep(const float* __restrict__ cb,
                                               __bf16* __restrict__ cbh,
                                               __bf16* __restrict__ cbf,
                                               float* __restrict__ sc1) {
    const int t = threadIdx.x;
    const int r = blockIdx.x * 16 + (t >> 4);
    const int d0 = (t & 15) * 16;
    const float* src = cb + (size_t)r * 256 + d0;
    __bf16* dst = cbh + (size_t)r * 256 + d0;
    float s = 0.f;
    float4 f[4];
    #pragma unroll
    for (int p = 0; p < 4; p++) f[p] = *(const float4*)(src + p * 4);
    bf16x8 v0, v1;
    #pragma unroll
    for (int p = 0; p < 4; p++) {
        s = fmaf(f[p].x, f[p].x, s); s = fmaf(f[p].y, f[p].y, s);
        s = fmaf(f[p].z, f[p].z, s); s = fmaf(f[p].w, f[p].w, s);
    }
    v0[0]=(__bf16)f[0].x; v0[1]=(__bf16)f[0].y; v0[2]=(__bf16)f[0].z; v0[3]=(__bf16)f[0].w;
    v0[4]=(__bf16)f[1].x; v0[5]=(__bf16)f[1].y; v0[6]=(__bf16)f[1].z; v0[7]=(__bf16)f[1].w;
    v1[0]=(__bf16)f[2].x; v1[1]=(__bf16)f[2].y; v1[2]=(__bf16)f[2].z; v1[3]=(__bf16)f[2].w;
    v1[4]=(__bf16)f[3].x; v1[5]=(__bf16)f[3].y; v1[6]=(__bf16)f[3].z; v1[7]=(__bf16)f[3].w;
    *(bf16x8*)dst = v0;
    *(bf16x8*)(dst + 8) = v1;
    // frag-major: tile = r>>4, chunk = d0>>5, lane slot = (r&15)*4 + ((d0>>3)&3)
    {
        const int slot = ((r >> 4) * 8 + (d0 >> 5)) * 512 + ((r & 15) * 4 + ((d0 >> 3) & 3)) * 8;
        *(bf16x8*)&cbf[slot]     = v0;
        *(bf16x8*)&cbf[slot + 8] = v1;
    }
    s += __shfl_xor(s, 1, 64);
    s += __shfl_xor(s, 2, 64);
    s += __shfl_xor(s, 4, 64);
    s += __shfl_xor(s, 8, 64);
    if ((t & 15) == 0) sc1[r] = s + 1.0f;
}

// ---------------- Kernel 2: MFMA distance-GEMM + argmin + outputs ----------------
// Block: 64 n-rows x all 1024 codes. 4 waves: each wave all 64 rows (4 row-frags)
// x its own 32 codes (2 frags) of each 128-code chunk. LDS 32 KB z tile [64][256]
// bf16, XOR-swizzled; recycled as argmin scratch, then as chosen-q tile for
// coalesced emit. No barriers in K-loop; B prefetched 4 steps ahead. 1024 blocks,
// kt-rotated per block.
__global__ __launch_bounds__(256, 2) void vq_mfma(const float* __restrict__ z,
                                                  const __bf16* __restrict__ cbh,
                                                  const __bf16* __restrict__ cbf,
                                                  const float* __restrict__ sc1,
                                                  float* __restrict__ out) {
    __shared__ __align__(16) __bf16 z_s[64 * 256];    // 32768 B
    __shared__ float red_s[4];

    const int t    = threadIdx.x;
    const int lane = t & 63;
    const int w    = t >> 6;
    const int m16  = lane & 15;
    const int q4   = lane >> 4;
    const int wc   = w << 5;              // wave's code offset within a 128-chunk
    const int lidx = m16 * 4 + q4;        // frag-major lane slot
    const int blk  = blockIdx.x;
    const int b    = blk >> 4;
    const int hw0  = (blk & 15) << 6;
    const int n0   = blk << 6;
    const int kt0  = (blk & 3) << 8;      // rotated code-sweep start (desync L2 streams)

    // B pipeline prologue: steps 0..3 of the first chunk, in flight during phase A
    bf16x8 bq[4][2];
    {
        const __bf16* bp = cbf + (size_t)((kt0 + wc) >> 4) * 4096 + lidx * 8;
        #pragma unroll
        for (int d = 0; d < 4; d++) {
            bq[d][0] = *(const bf16x8*)(bp + d * 512);
            bq[d][1] = *(const bf16x8*)(bp + d * 512 + 4096);
        }
    }

    // ---- phase A: stage z (fp32 global, float4 along hw) -> bf16 LDS [n][d]; sum z^2
    float lz = 0.f;
    {
        const int rg    = (t & 15) * 4;       // 4-row group
        const int dbase = (t >> 4) * 16;      // 16 d's per thread
        const float* zp = z + (size_t)b * 262144 + hw0 + rg;
        #pragma unroll
        for (int batch = 0; batch < 2; batch++) {
            float4 f[8];
            #pragma unroll
            for (int j = 0; j < 8; j++)
                f[j] = *(const float4*)(zp + (size_t)(dbase + batch * 8 + j) * 1024);
            const float* fp = (const float*)f;
            #pragma unroll
            for (int r = 0; r < 4; r++) {
                bf16x8 v;
                #pragma unroll
                for (int j = 0; j < 8; j++) {
                    float x = fp[j * 4 + r];
                    lz = fmaf(x, x, lz);
                    v[j] = (__bf16)x;
                }
                const int row = rg + r;
                const int gs  = ((t >> 4) * 2 + batch) ^ (row & 7);
                *(bf16x8*)&z_s[row * 256 + gs * 8] = v;
            }
        }
    }
    __syncthreads();

    // ---- GEMM + packed-uint running argmin (no barriers; 4-deep B pipeline)
    unsigned int best[16];
    #pragma unroll
    for (int i = 0; i < 16; i++) best[i] = 0xFFFFFFFFu;

    #pragma unroll 1
    for (int it = 0; it < 8; it++) {
        const int kt  = (kt0 + (it << 7)) & 1023;
        const int ktn = (kt0 + (((it + 1) & 7) << 7)) & 1023;
        // per-chunk code norms (+1) and packed indices — hidden under MFMAs
        int   kcv[2];
        float sck[2];
        #pragma unroll
        for (int j = 0; j < 2; j++) {
            kcv[j] = kt + wc + j * 16 + m16;
            sck[j] = sc1[kcv[j]];
        }
        // frag-major bases: tile stride 4096 elems, chunk stride 512 elems
        const __bf16* bt  = cbf + (size_t)((kt  + wc) >> 4) * 4096 + lidx * 8;
        const __bf16* btn = cbf + (size_t)((ktn + wc) >> 4) * 4096 + lidx * 8;

        f32x4 acc[4][2];
        #pragma unroll
        for (int i = 0; i < 4; i++)
            #pragma unroll
            for (int j = 0; j < 2; j++) acc[i][j] = (f32x4){0.f, 0.f, 0.f, 0.f};

        #pragma unroll
        for (int dcs = 0; dcs < 8; dcs++) {
            // prefetch step dcs+4 of the global sweep (crosses into next chunk at dcs>=4;
            // final chunk's tail prefetch wraps harmlessly, never consumed)
            bf16x8 bn0, bn1;
            {
                const __bf16* bp = (dcs < 4) ? (bt + (dcs + 4) * 512) : (btn + (dcs - 4) * 512);
                bn0 = *(const bf16x8*)bp;
                bn1 = *(const bf16x8*)(bp + 4096);
            }

            // A frags in-place; MFMA burst on the 4-step-old B pair
            const int gs = (dcs * 4 + q4) ^ (m16 & 7);
            #pragma unroll
            for (int i = 0; i < 4; i++) {
                bf16x8 a = *(const bf16x8*)&z_s[(i * 16 + m16) * 256 + gs * 8];
                acc[i][0] = __builtin_amdgcn_mfma_f32_16x16x32_bf16(a, bq[0][0], acc[i][0], 0, 0, 0);
                acc[i][1] = __builtin_amdgcn_mfma_f32_16x16x32_bf16(a, bq[0][1], acc[i][1], 0, 0, 0);
            }

            // rotate pipeline (SSA renames under full unroll)
            bq[0][0] = bq[1][0]; bq[0][1] = bq[1][1];
            bq[1][0] = bq[2][0]; bq[1][1] = bq[2][1];
            bq[2][0] = bq[3][0]; bq[2][1] = bq[3][1];
            bq[3][0] = bn0;      bq[3][1] = bn1;
        }

        // packed argmin: score = 1 + ||c||^2 - 2 z.c  > 0 always
        #pragma unroll
        for (int j = 0; j < 2; j++) {
            #pragma unroll
            for (int i = 0; i < 4; i++)
                #pragma unroll
                for (int r = 0; r < 4; r++) {
                    float v3 = fmaf(-2.f, acc[i][j][r], sck[j]);
                    unsigned int key = (__float_as_uint(v3) & 0xFFFFFC00u) | (unsigned int)kcv[j];
                    int pos = i * 4 + r;
                    best[pos] = min(best[pos], key);
                }
        }
    }

    // ---- intra-wave min across the 16 col-lanes
    #pragma unroll
    for (int pos = 0; pos < 16; pos++) {
        unsigned int k = best[pos];
        #pragma unroll
        for (int off = 1; off < 16; off <<= 1)
            k = min(k, (unsigned int)__shfl_xor((int)k, off, 64));
        best[pos] = k;
    }
    __syncthreads();              // all z_s reads done -> z_s becomes scratch

    // ---- cross-wave combine in recycled z_s
    // ks[0..256): key[wave][row] (each wave owns a distinct code quarter);
    // ks[256..320): chosen k
    unsigned int* ks = (unsigned int*)z_s;
    if (m16 == 0) {
        #pragma unroll
        for (int pos = 0; pos < 16; pos++) {
            int i = pos >> 2, r = pos & 3;
            int row = i * 16 + q4 * 4 + r;
            ks[w * 64 + row] = best[pos];
        }
    }
    __syncthreads();
    if (t < 64) {
        unsigned int key = min(min(ks[t], ks[64 + t]), min(ks[128 + t], ks[192 + t]));
        int kf = (int)(key & 1023u);
        ks[256 + t] = (unsigned int)kf;
        out[IDX_OFF + n0 + t] = (float)kf;
        lz += __uint_as_float(key & 0xFFFFFC00u) - 1.0f;   // best score (unshifted)
    }
    {
        float s = lz;
        #pragma unroll
        for (int off = 1; off < 64; off <<= 1) s += __shfl_xor(s, off, 64);
        if (lane == 0) red_s[w] = s;
    }
    __syncthreads();              // ks[256..320) and red_s visible
    if (t == 0)
        atomicAdd(out + LOSS_OFF, 1.25f * ((red_s[0] + red_s[1]) + (red_s[2] + red_s[3])));

    // ---- stage chosen codebook rows into z_s, then coalesced emit
    const int qrow = t >> 2;              // 0..63
    const int qoff = (t & 3) * 64;        // d offset 0/64/128/192
    const int myk  = (int)ks[256 + qrow];
    __syncthreads();              // everyone read their k; safe to overwrite z_s
    {
        const __bf16* qp = cbh + (size_t)myk * 256 + qoff;
        #pragma unroll
        for (int p = 0; p < 8; p++) {
            bf16x8 v = *(const bf16x8*)(qp + p * 8);
            int gs = ((qoff >> 3) + p) ^ (qrow & 7);
            *(bf16x8*)&z_s[qrow * 256 + gs * 8] = v;
        }
    }
    __syncthreads();
    {
        const int nl   = t & 63;
        const int dseg = t >> 6;
        float* op = out + (size_t)(b * 256 + dseg * 64) * 1024 + hw0 + nl;
        #pragma unroll
        for (int p = 0; p < 8; p++) {
            int gs = (dseg * 8 + p) ^ (nl & 7);
            bf16x8 v = *(const bf16x8*)&z_s[nl * 256 + gs * 8];
            #pragma unroll
            for (int j = 0; j < 8; j++)
                op[(size_t)(p * 8 + j) * 1024] = (float)v[j];
        }
    }
}

extern "C" void kernel_launch(void* const* d_in, const int* in_sizes, int n_in,
                              void* d_out, int out_size, void* d_ws, size_t ws_size,
                              hipStream_t stream) {
    const float* z  = (const float*)d_in[0];   // 16777216
    const float* cb = (const float*)d_in[1];   // 262144
    float* out = (float*)d_out;

    float*  sc1 = (float*)d_ws;                             // 1024 f  (1 + ||c||^2)
    __bf16* cbh = (__bf16*)((char*)d_ws + 8192);            // 512 KB bf16 codebook (row-major)
    __bf16* cbf = (__bf16*)((char*)d_ws + 8192 + 524288);   // 512 KB bf16 codebook (frag-major)

    hipMemsetAsync(out + LOSS_OFF, 0, sizeof(float), stream);   // capture-safe
    vq_prep<<<64, 256, 0, stream>>>(cb, cbh, cbf, sc1);
    vq_mfma<<<1024, 256, 0, stream>>>(z, cbh, cbf, sc1, out);
}